// Round 12
// baseline (73.321 us; speedup 1.0000x reference)
//
#include <hip/hip_runtime.h>
#include <hip/hip_bf16.h>

constexpr int HID = 1024;
constexpr int KD  = 16;    // probe directions
constexpr int TM  = 16;    // rows per tile
constexpr int NW  = 4;     // waves per block (each owns a 256-wide K slice)

typedef short bf16x8 __attribute__((ext_vector_type(8)));   // MFMA A/B frag
typedef float f32x4  __attribute__((ext_vector_type(4)));   // MFMA C/D frag

__device__ __forceinline__ short f2b(float x) {
    __hip_bfloat16 b = __float2bfloat16(x);
    return *reinterpret_cast<short*>(&b);
}

// ---- setup: pre-transpose + pre-convert Q into workspace ----
// Qt[r][k] = bf16(Q[k][r])  (16 x 1024): coef B-frags = 16B contiguous reads
// Qa[c][d] = bf16(Q[c][d])  (1024 x 16): epilogue A-frags = 16B contiguous reads
__global__ void q_setup(const float* __restrict__ Qf,
                        short* __restrict__ Qt, short* __restrict__ Qa) {
    const int idx = blockIdx.x*256 + threadIdx.x;
    if (idx < 16*HID) {
        const int r = idx >> 10, k = idx & 1023;
        Qt[idx] = f2b(Qf[k*KD + r]);
        Qa[idx] = f2b(Qf[idx]);
    }
}

// Round-10 diagnosis: VGPR=44 gave the compiler a ~2-load prefetch window ->
// ~1KB/CU outstanding vs ~15KB needed -> 3.8 TB/s latency-bound. This round:
// identical structure, but HAND-PIPELINED loads. Coef: all 8 bq frags
// preloaded + 4-deep register stage of H float4 pairs (~8 loads in flight
// per lane). Epilogue: 3-deep stage of (Qa frag, h reload). All stage
// indices are static after full unroll (no scratch).
__global__ __launch_bounds__(NW*64)
void probe_removal_w4p(const float* __restrict__ H,
                       const short* __restrict__ Qt,
                       const short* __restrict__ Qa,
                       float* __restrict__ out)
{
    const int lane = threadIdx.x & 63;
    const int w    = threadIdx.x >> 6;   // wave 0..3: K-slice [w*256, w*256+256)
    const int r    = lane & 15;
    const int q    = lane >> 4;
    const int tile = blockIdx.x;

    __shared__ __align__(16) float ctr[NW][TM][20];  // C partials [wave][row][dir]
    __shared__ float s2p[NW][TM];                    // ||h||^2 partials

    const float* hrow   = H + (size_t)tile*TM*HID + r*HID;   // lane's row (f32)
    const int colbase   = w*256 + q*8;               // coef-phase column base

    // ---- preload all 8 coef B-frags (L2-hot Qt, 32 regs) ----
    bf16x8 bq[8];
    #pragma unroll
    for (int kt = 0; kt < 8; ++kt)
        bq[kt] = *reinterpret_cast<const bf16x8*>(Qt + r*1024 + colbase + kt*32);

    // ---- coef GEMM with 4-deep explicit load stage ----
    float4 sx[4], sy[4];
    #pragma unroll
    for (int p = 0; p < 4; ++p) {
        sx[p] = *reinterpret_cast<const float4*>(hrow + colbase + p*32);
        sy[p] = *reinterpret_cast<const float4*>(hrow + colbase + p*32 + 4);
    }
    f32x4 acc0 = {0.f,0.f,0.f,0.f}, acc1 = {0.f,0.f,0.f,0.f};
    float s2 = 0.f;
    #pragma unroll
    for (int kt = 0; kt < 8; ++kt) {
        const float4 x = sx[kt & 3], y = sy[kt & 3];
        if (kt < 4) {   // refill the slot 4 iterations ahead
            sx[kt & 3] = *reinterpret_cast<const float4*>(hrow + colbase + (kt+4)*32);
            sy[kt & 3] = *reinterpret_cast<const float4*>(hrow + colbase + (kt+4)*32 + 4);
        }
        s2 = fmaf(x.x,x.x, fmaf(x.y,x.y, fmaf(x.z,x.z, fmaf(x.w,x.w, s2))));
        s2 = fmaf(y.x,y.x, fmaf(y.y,y.y, fmaf(y.z,y.z, fmaf(y.w,y.w, s2))));
        bf16x8 af;
        af[0]=f2b(x.x); af[1]=f2b(x.y); af[2]=f2b(x.z); af[3]=f2b(x.w);
        af[4]=f2b(y.x); af[5]=f2b(y.y); af[6]=f2b(y.z); af[7]=f2b(y.w);
        if (kt & 1) acc1 = __builtin_amdgcn_mfma_f32_16x16x32_bf16(af, bq[kt], acc1, 0, 0, 0);
        else        acc0 = __builtin_amdgcn_mfma_f32_16x16x32_bf16(af, bq[kt], acc0, 0, 0, 0);
    }
    const f32x4 acc = acc0 + acc1;
    s2 += __shfl_xor(s2, 16);          // combine q-groups: s2 partial for row r
    s2 += __shfl_xor(s2, 32);

    #pragma unroll
    for (int i = 0; i < 4; ++i) ctr[w][q*4 + i][r] = acc[i];   // C[m=q*4+i][n=dir=r]
    if (q == 0) s2p[w][r] = s2;

    __syncthreads();   // the ONLY barrier in the kernel

    // ---- reduce over the 4 waves -> coefs for row r, scale ----
    float cf[8] = {0,0,0,0,0,0,0,0};
    if (q < 2) {
        #pragma unroll
        for (int w2 = 0; w2 < NW; ++w2) {
            const float4 a = *reinterpret_cast<const float4*>(&ctr[w2][r][q*8]);
            const float4 b = *reinterpret_cast<const float4*>(&ctr[w2][r][q*8 + 4]);
            cf[0]+=a.x; cf[1]+=a.y; cf[2]+=a.z; cf[3]+=a.w;
            cf[4]+=b.x; cf[5]+=b.y; cf[6]+=b.z; cf[7]+=b.w;
        }
    }
    float s2tot = 0.f;
    #pragma unroll
    for (int w2 = 0; w2 < NW; ++w2) s2tot += s2p[w2][r];   // broadcast reads

    float sc2 = 0.f;
    #pragma unroll
    for (int i = 0; i < 8; ++i) sc2 = fmaf(cf[i], cf[i], sc2);
    sc2 += __shfl_xor(sc2, 16);
    sc2 += __shfl_xor(sc2, 32);
    const float scale = rsqrtf(fmaxf(1.0f - sc2 / s2tot, 1e-20f));

    bf16x8 pb;   // B[k=dir][n=row=r]; q>=2 lanes carry the K-pad zeros
    #pragma unroll
    for (int i = 0; i < 8; ++i) pb[i] = f2b(cf[i]);

    // ---- epilogue with 3-deep (Qa, h) stage: wave w covers 16 col-tiles ----
    float* orow = out + (size_t)tile*TM*HID + r*HID;
    const int ecol = q*4;
    const f32x4 zero4 = {0.f,0.f,0.f,0.f};

    bf16x8 qa_s[3];
    float4 h_s[3];
    #pragma unroll
    for (int p = 0; p < 3; ++p) {
        const int j = w*16 + p;
        if (q < 2) {
            qa_s[p] = *reinterpret_cast<const bf16x8*>(Qa + (j*16 + r)*KD + q*8);
        } else {
            #pragma unroll
            for (int i = 0; i < 8; ++i) qa_s[p][i] = 0;
        }
        h_s[p] = *reinterpret_cast<const float4*>(hrow + j*16 + ecol);
    }
    #pragma unroll
    for (int jj = 0; jj < 16; ++jj) {
        const int j = w*16 + jj;
        const bf16x8 aj = qa_s[jj % 3];
        const float4 hx = h_s[jj % 3];
        if (jj < 13) {   // refill slot 3 ahead
            const int jn = w*16 + jj + 3;
            if (q < 2) {
                qa_s[jj % 3] = *reinterpret_cast<const bf16x8*>(Qa + (jn*16 + r)*KD + q*8);
            }
            h_s[jj % 3] = *reinterpret_cast<const float4*>(hrow + jn*16 + ecol);
        }
        const f32x4 d = __builtin_amdgcn_mfma_f32_16x16x32_bf16(aj, pb, zero4, 0, 0, 0);
        // lane(r,q) holds out[row r][j*16 + q*4 + 0..3]
        f32x4 o;
        o[0] = (hx.x - d[0]) * scale;
        o[1] = (hx.y - d[1]) * scale;
        o[2] = (hx.z - d[2]) * scale;
        o[3] = (hx.w - d[3]) * scale;
        // plain store: L2 write-back merges quads into full 128B lines
        *reinterpret_cast<f32x4*>(orow + j*16 + ecol) = o;
    }
}

extern "C" void kernel_launch(void* const* d_in, const int* in_sizes, int n_in,
                              void* d_out, int out_size, void* d_ws, size_t ws_size,
                              hipStream_t stream) {
    const float* H  = (const float*)d_in[0];   // [8,4096,1024] f32
    const float* Qf = (const float*)d_in[1];   // [1024,16] f32, orthonormal cols
    float* outp     = (float*)d_out;
    const int nrows  = in_sizes[0] / HID;      // 32768
    const int ntiles = nrows / TM;             // 2048

    short* Qt = (short*)d_ws;                  // 32 KB
    short* Qa = Qt + 16*HID;                   // 32 KB

    hipLaunchKernelGGL(q_setup, dim3(64), dim3(256), 0, stream, Qf, Qt, Qa);

    // one 16-row tile per 4-wave block; 2048 blocks -> all-resident
    hipLaunchKernelGGL(probe_removal_w4p, dim3(ntiles), dim3(NW*64), 0, stream,
                       H, Qt, Qa, outp);
}

// Round 13
// 61.764 us; speedup vs baseline: 1.1871x; 1.1871x over previous
//
#include <hip/hip_runtime.h>
#include <hip/hip_bf16.h>

constexpr int HID = 1024;
constexpr int KD  = 16;    // probe directions
constexpr int TM  = 16;    // rows per tile
constexpr int NW  = 4;     // waves per block (each owns a 256-wide col slice)

typedef short bf16x8 __attribute__((ext_vector_type(8)));   // MFMA A/B frag
typedef float f32x4  __attribute__((ext_vector_type(4)));   // MFMA C/D frag

__device__ __forceinline__ short f2b(float x) {
    __hip_bfloat16 b = __float2bfloat16(x);
    return *reinterpret_cast<short*>(&b);
}
__device__ __forceinline__ float b2f(short s) {
    return __uint_as_float(((unsigned int)(unsigned short)s) << 16);
}

// ---- setup: build both Q tables in workspace ----
// Qt[r][k] = bf16(Q[k][r])            (16 x 1024): coef B-frags, 16B reads
// Qa_perm[jslot][r'][dir]             (64 x 16 x 16): epilogue A-frags,
//   COLUMN-PERMUTED so the epilogue MFMA's D-layout lands exactly on the
//   coef A-frag layout: tile 2p covers cols {p*32+q*8+0..3}, tile 2p+1
//   covers {p*32+q*8+4..7}.  col(jslot,r') = w*256 + p*32 + (r'>>2)*8
//   + (jslot&1)*4 + (r'&3),  w=jslot>>4, p=(jslot&15)>>1.
__global__ void q_setup(const float* __restrict__ Qf,
                        short* __restrict__ Qt, short* __restrict__ Qa) {
    const int idx = blockIdx.x*256 + threadIdx.x;    // 0..16383
    if (idx < 16*HID) {
        const int r = idx >> 10, k = idx & 1023;
        Qt[idx] = f2b(Qf[k*KD + r]);

        const int gs = idx >> 4, dir = idx & 15;     // gs = jslot*16 + r'
        const int jslot = gs >> 4, rr = gs & 15;
        const int w = jslot >> 4, jl = jslot & 15;
        const int p = jl >> 1, odd = jl & 1;
        const int col = w*256 + p*32 + (rr >> 2)*8 + odd*4 + (rr & 3);
        Qa[idx] = f2b(Qf[col*KD + dir]);
    }
}

// Single H read: coef A-frags (af[8], bf16, 32 VGPR) are kept in registers
// and reused as the h term in the epilogue. The permuted Qa makes the
// epilogue MFMA output register-aligned with af -> no re-read, no shuffle.
__global__ __launch_bounds__(NW*64)
void probe_removal_fused(const float* __restrict__ H,
                         const short* __restrict__ Qt,
                         const short* __restrict__ Qa,
                         float* __restrict__ out)
{
    const int lane = threadIdx.x & 63;
    const int w    = threadIdx.x >> 6;   // wave: col slice [w*256, w*256+256)
    const int r    = lane & 15;
    const int q    = lane >> 4;
    const int tile = blockIdx.x;

    __shared__ __align__(16) float ctr[NW][TM][20];  // C partials [wave][row][dir]
    __shared__ float s2p[NW][TM];                    // ||h||^2 partials

    const float* hrow   = H + (size_t)tile*TM*HID + r*HID;
    const int   colbase = w*256 + q*8;

    // ---- coef B-frags from Qt (L2-hot, 32 VGPR, freed after coef phase) ----
    bf16x8 bq[8];
    #pragma unroll
    for (int kt = 0; kt < 8; ++kt)
        bq[kt] = *reinterpret_cast<const bf16x8*>(Qt + r*1024 + colbase + kt*32);

    // ---- coef GEMM over the wave's 256 cols; af[] = lane's H slice in bf16 ----
    bf16x8 af[8];
    f32x4 acc0 = {0.f,0.f,0.f,0.f}, acc1 = {0.f,0.f,0.f,0.f};
    float s2 = 0.f;
    #pragma unroll
    for (int kt = 0; kt < 8; ++kt) {
        const float4 x = *reinterpret_cast<const float4*>(hrow + colbase + kt*32);
        const float4 y = *reinterpret_cast<const float4*>(hrow + colbase + kt*32 + 4);
        s2 = fmaf(x.x,x.x, fmaf(x.y,x.y, fmaf(x.z,x.z, fmaf(x.w,x.w, s2))));
        s2 = fmaf(y.x,y.x, fmaf(y.y,y.y, fmaf(y.z,y.z, fmaf(y.w,y.w, s2))));
        bf16x8 a;
        a[0]=f2b(x.x); a[1]=f2b(x.y); a[2]=f2b(x.z); a[3]=f2b(x.w);
        a[4]=f2b(y.x); a[5]=f2b(y.y); a[6]=f2b(y.z); a[7]=f2b(y.w);
        af[kt] = a;
        if (kt & 1) acc1 = __builtin_amdgcn_mfma_f32_16x16x32_bf16(a, bq[kt], acc1, 0, 0, 0);
        else        acc0 = __builtin_amdgcn_mfma_f32_16x16x32_bf16(a, bq[kt], acc0, 0, 0, 0);
    }
    const f32x4 acc = acc0 + acc1;
    s2 += __shfl_xor(s2, 16);          // combine q-groups: row-r partial
    s2 += __shfl_xor(s2, 32);

    #pragma unroll
    for (int i = 0; i < 4; ++i) ctr[w][q*4 + i][r] = acc[i];   // C[row q*4+i][dir r]
    if (q == 0) s2p[w][r] = s2;

    __syncthreads();   // the ONLY barrier

    // ---- reduce over 4 waves -> coefs for row r, scale ----
    float cf[8] = {0,0,0,0,0,0,0,0};
    if (q < 2) {
        #pragma unroll
        for (int w2 = 0; w2 < NW; ++w2) {
            const float4 a = *reinterpret_cast<const float4*>(&ctr[w2][r][q*8]);
            const float4 b = *reinterpret_cast<const float4*>(&ctr[w2][r][q*8 + 4]);
            cf[0]+=a.x; cf[1]+=a.y; cf[2]+=a.z; cf[3]+=a.w;
            cf[4]+=b.x; cf[5]+=b.y; cf[6]+=b.z; cf[7]+=b.w;
        }
    }
    float s2tot = 0.f;
    #pragma unroll
    for (int w2 = 0; w2 < NW; ++w2) s2tot += s2p[w2][r];   // broadcast reads

    float sc2 = 0.f;
    #pragma unroll
    for (int i = 0; i < 8; ++i) sc2 = fmaf(cf[i], cf[i], sc2);
    sc2 += __shfl_xor(sc2, 16);
    sc2 += __shfl_xor(sc2, 32);
    const float scale = rsqrtf(fmaxf(1.0f - sc2 / s2tot, 1e-20f));

    bf16x8 pb;   // B[k=dir][n=row r]; q>=2 lanes carry the K-pad zeros
    #pragma unroll
    for (int i = 0; i < 8; ++i) pb[i] = f2b(cf[i]);

    // ---- epilogue: all operands in registers or L2-hot Qa; no h re-read ----
    // pair p: tiles 2p (cols p*32+q*8+0..3) and 2p+1 (cols p*32+q*8+4..7);
    // d0[ii] / d1[ii] align exactly with af[p][ii] / af[p][4+ii].
    float* orow = out + (size_t)tile*TM*HID + r*HID + w*256;
    const f32x4 zero4 = {0.f,0.f,0.f,0.f};
    #pragma unroll
    for (int p = 0; p < 8; ++p) {
        bf16x8 a0, a1;
        if (q < 2) {
            a0 = *reinterpret_cast<const bf16x8*>(Qa + ((w*16 + 2*p    )*16 + r)*KD + q*8);
            a1 = *reinterpret_cast<const bf16x8*>(Qa + ((w*16 + 2*p + 1)*16 + r)*KD + q*8);
        } else {
            #pragma unroll
            for (int i = 0; i < 8; ++i) { a0[i] = 0; a1[i] = 0; }
        }
        const f32x4 d0 = __builtin_amdgcn_mfma_f32_16x16x32_bf16(a0, pb, zero4, 0, 0, 0);
        const f32x4 d1 = __builtin_amdgcn_mfma_f32_16x16x32_bf16(a1, pb, zero4, 0, 0, 0);
        f32x4 o0, o1;
        #pragma unroll
        for (int ii = 0; ii < 4; ++ii) {
            o0[ii] = (b2f(af[p][ii])     - d0[ii]) * scale;
            o1[ii] = (b2f(af[p][4 + ii]) - d1[ii]) * scale;
        }
        // back-to-back stores: the two 16B pieces per lane fill each 128B
        // line completely across the 4 q-lanes -> full-line writebacks
        *reinterpret_cast<f32x4*>(orow + p*32 + q*8)     = o0;
        *reinterpret_cast<f32x4*>(orow + p*32 + q*8 + 4) = o1;
    }
}

extern "C" void kernel_launch(void* const* d_in, const int* in_sizes, int n_in,
                              void* d_out, int out_size, void* d_ws, size_t ws_size,
                              hipStream_t stream) {
    const float* H  = (const float*)d_in[0];   // [8,4096,1024] f32
    const float* Qf = (const float*)d_in[1];   // [1024,16] f32, orthonormal cols
    float* outp     = (float*)d_out;
    const int nrows  = in_sizes[0] / HID;      // 32768
    const int ntiles = nrows / TM;             // 2048

    short* Qt = (short*)d_ws;                  // 32 KB
    short* Qa = Qt + 16*HID;                   // 32 KB (permuted)

    hipLaunchKernelGGL(q_setup, dim3(64), dim3(256), 0, stream, Qf, Qt, Qa);
    hipLaunchKernelGGL(probe_removal_fused, dim3(ntiles), dim3(NW*64), 0, stream,
                       H, Qt, Qa, outp);
}

// Round 14
// 58.117 us; speedup vs baseline: 1.2616x; 1.0628x over previous
//
#include <hip/hip_runtime.h>
#include <hip/hip_bf16.h>

constexpr int HID = 1024;
constexpr int KD  = 16;    // probe directions
constexpr int TM  = 16;    // rows per tile
constexpr int NW  = 4;     // waves per block
constexpr int TPB = 8;     // tiles per block (2048 tiles / 256 blocks)

typedef short bf16x8 __attribute__((ext_vector_type(8)));   // MFMA A/B frag
typedef float f32x4  __attribute__((ext_vector_type(4)));   // MFMA C/D frag

__device__ __forceinline__ short f2b(float x) {
    __hip_bfloat16 b = __float2bfloat16(x);
    return *reinterpret_cast<short*>(&b);
}
__device__ __forceinline__ float b2f(short s) {
    return __uint_as_float(((unsigned int)(unsigned short)s) << 16);
}

// Qt[r][k] = bf16(Q[k][r]) (16x1024): coef B-frags, 16B contiguous reads.
// Qa permuted (64x16x16): epilogue A-frags such that the epilogue MFMA's
// D-layout lands exactly on the coef A-frag register layout (R13, verified).
__global__ void q_setup(const float* __restrict__ Qf,
                        short* __restrict__ Qt, short* __restrict__ Qa) {
    const int idx = blockIdx.x*256 + threadIdx.x;
    if (idx < 16*HID) {
        const int r = idx >> 10, k = idx & 1023;
        Qt[idx] = f2b(Qf[k*KD + r]);
        const int gs = idx >> 4, dir = idx & 15;
        const int jslot = gs >> 4, rr = gs & 15;
        const int w = jslot >> 4, jl = jslot & 15;
        const int p = jl >> 1, odd = jl & 1;
        const int col = w*256 + p*32 + (rr >> 2)*8 + odd*4 + (rr & 3);
        Qa[idx] = f2b(Qf[col*KD + dir]);
    }
}

#define SCHED_FENCE() __builtin_amdgcn_sched_barrier(0)

// Stage one 64KB H tile via global_load_lds: wave w stages rows w*4..w*4+3.
// Piece (16B) swizzle ^ (row&7) applied on the GLOBAL source address (LDS
// dest stays linear, as global_load_lds requires); the coef ds_read applies
// the same XOR -> ~conflict-free b128 reads.
__device__ __forceinline__ void stage_tile(float* ldsBuf, const float* Hbase,
                                           int w, int lane) {
    #pragma unroll
    for (int i = 0; i < 16; ++i) {
        const int rr = w*4 + (i >> 2);
        const int qq = i & 3;
        const int s  = qq*64 + lane;                  // lds piece slot
        const float* g = Hbase + rr*1024 + ((s ^ (rr & 7)) << 2);
        const float* l = ldsBuf + rr*1024 + qq*256;   // wave-uniform base; HW adds lane*16
        __builtin_amdgcn_global_load_lds(
            (const __attribute__((address_space(1))) void*)g,
            (__attribute__((address_space(3))) void*)l, 16, 0, 0);
    }
}

__global__ __launch_bounds__(NW*64)
void probe_removal_dma(const float* __restrict__ H,
                       const short* __restrict__ Qt,
                       const short* __restrict__ Qa,
                       float* __restrict__ out)
{
    const int lane = threadIdx.x & 63;
    const int w    = threadIdx.x >> 6;   // wave: col slice [w*256, w*256+256)
    const int r    = lane & 15;
    const int q    = lane >> 4;

    __shared__ __align__(16) float Hb[2][TM][HID];   // 128 KB double buffer
    __shared__ __align__(16) float ctr[NW][TM][20];  // coef partials
    __shared__ float s2p[NW][TM];

    const int tile0 = blockIdx.x * TPB;

    // ---- persistent Q fragments (96 VGPR; 1 block/CU -> budget ~512, no spill) ----
    bf16x8 bq[8];                       // coef B-frag per kt
    #pragma unroll
    for (int kt = 0; kt < 8; ++kt)
        bq[kt] = *reinterpret_cast<const bf16x8*>(Qt + r*1024 + w*256 + q*8 + kt*32);
    bf16x8 aq0[8], aq1[8];              // epilogue A-frag pairs (permuted Qa)
    #pragma unroll
    for (int p = 0; p < 8; ++p) {
        if (q < 2) {
            aq0[p] = *reinterpret_cast<const bf16x8*>(Qa + ((w*16 + 2*p    )*16 + r)*KD + q*8);
            aq1[p] = *reinterpret_cast<const bf16x8*>(Qa + ((w*16 + 2*p + 1)*16 + r)*KD + q*8);
        } else {
            #pragma unroll
            for (int i = 0; i < 8; ++i) { aq0[p][i] = 0; aq1[p][i] = 0; }
        }
    }
    SCHED_FENCE();

    // ---- prologue: stage tiles 0 and 1 ----
    stage_tile(&Hb[0][0][0], H + (size_t)tile0*TM*HID, w, lane);
    SCHED_FENCE();
    stage_tile(&Hb[1][0][0], H + (size_t)(tile0+1)*TM*HID, w, lane);
    SCHED_FENCE();
    asm volatile("s_waitcnt vmcnt(16)" ::: "memory");   // tile 0 landed (tile 1 in flight)
    SCHED_FENCE();
    __builtin_amdgcn_s_barrier();

    #pragma unroll
    for (int t = 0; t < TPB; ++t) {
        const int cur = t & 1;
        const char* HbC = (const char*)&Hb[cur][0][0];

        // ---- coef GEMM from LDS (swizzled b128 reads); af = h slice in regs ----
        bf16x8 af[8];
        f32x4 acc0 = {0.f,0.f,0.f,0.f}, acc1 = {0.f,0.f,0.f,0.f};
        float s2 = 0.f;
        #pragma unroll
        for (int kt = 0; kt < 8; ++kt) {
            const int P  = w*64 + kt*8 + q*2;       // even
            const int sx = P ^ (r & 7);
            const float4 x = *(const float4*)(HbC + r*4096 + sx*16);
            const float4 y = *(const float4*)(HbC + r*4096 + (sx^1)*16);
            s2 = fmaf(x.x,x.x, fmaf(x.y,x.y, fmaf(x.z,x.z, fmaf(x.w,x.w, s2))));
            s2 = fmaf(y.x,y.x, fmaf(y.y,y.y, fmaf(y.z,y.z, fmaf(y.w,y.w, s2))));
            bf16x8 a;
            a[0]=f2b(x.x); a[1]=f2b(x.y); a[2]=f2b(x.z); a[3]=f2b(x.w);
            a[4]=f2b(y.x); a[5]=f2b(y.y); a[6]=f2b(y.z); a[7]=f2b(y.w);
            af[kt] = a;
            if (kt & 1) acc1 = __builtin_amdgcn_mfma_f32_16x16x32_bf16(a, bq[kt], acc1, 0, 0, 0);
            else        acc0 = __builtin_amdgcn_mfma_f32_16x16x32_bf16(a, bq[kt], acc0, 0, 0, 0);
        }
        const f32x4 acc = acc0 + acc1;
        s2 += __shfl_xor(s2, 16);
        s2 += __shfl_xor(s2, 32);

        #pragma unroll
        for (int i = 0; i < 4; ++i) ctr[w][q*4 + i][r] = acc[i];
        if (q == 0) s2p[w][r] = s2;

        // ctr visible to all waves; does NOT drain vmcnt (raw barrier):
        asm volatile("s_waitcnt lgkmcnt(0)" ::: "memory");
        SCHED_FENCE();
        __builtin_amdgcn_s_barrier();
        SCHED_FENCE();

        // ---- stage tile t+2 into the buffer just freed (all coef reads done) ----
        if (t + 2 < TPB)
            stage_tile(&Hb[cur][0][0], H + (size_t)(tile0+t+2)*TM*HID, w, lane);
        SCHED_FENCE();

        // ---- cross-wave reduce -> coefs, scale, pb ----
        float cf[8] = {0,0,0,0,0,0,0,0};
        if (q < 2) {
            #pragma unroll
            for (int w2 = 0; w2 < NW; ++w2) {
                const float4 a = *reinterpret_cast<const float4*>(&ctr[w2][r][q*8]);
                const float4 b = *reinterpret_cast<const float4*>(&ctr[w2][r][q*8 + 4]);
                cf[0]+=a.x; cf[1]+=a.y; cf[2]+=a.z; cf[3]+=a.w;
                cf[4]+=b.x; cf[5]+=b.y; cf[6]+=b.z; cf[7]+=b.w;
            }
        }
        float s2tot = 0.f;
        #pragma unroll
        for (int w2 = 0; w2 < NW; ++w2) s2tot += s2p[w2][r];

        float sc2 = 0.f;
        #pragma unroll
        for (int i = 0; i < 8; ++i) sc2 = fmaf(cf[i], cf[i], sc2);
        sc2 += __shfl_xor(sc2, 16);
        sc2 += __shfl_xor(sc2, 32);
        const float scale = rsqrtf(fmaxf(1.0f - sc2 / s2tot, 1e-20f));

        bf16x8 pb;
        #pragma unroll
        for (int i = 0; i < 8; ++i) pb[i] = f2b(cf[i]);

        // ---- fused epilogue: everything in registers; only the 16 stores ----
        float* orow = out + (size_t)(tile0+t)*TM*HID + r*HID + w*256;
        const f32x4 zero4 = {0.f,0.f,0.f,0.f};
        #pragma unroll
        for (int p = 0; p < 8; ++p) {
            const f32x4 d0 = __builtin_amdgcn_mfma_f32_16x16x32_bf16(aq0[p], pb, zero4, 0, 0, 0);
            const f32x4 d1 = __builtin_amdgcn_mfma_f32_16x16x32_bf16(aq1[p], pb, zero4, 0, 0, 0);
            f32x4 o0, o1;
            #pragma unroll
            for (int ii = 0; ii < 4; ++ii) {
                o0[ii] = (b2f(af[p][ii])     - d0[ii]) * scale;
                o1[ii] = (b2f(af[p][4 + ii]) - d1[ii]) * scale;
            }
            *reinterpret_cast<f32x4*>(orow + p*32 + q*8)     = o0;
            *reinterpret_cast<f32x4*>(orow + p*32 + q*8 + 4) = o1;
        }
        SCHED_FENCE();

        // ---- counted drain: tile t+1 landed; t+2 stage + this tile's stores
        //      stay in flight (never vmcnt(0) mid-loop) ----
        if (t < TPB-2)       { asm volatile("s_waitcnt vmcnt(32)" ::: "memory"); }
        else if (t == TPB-2) { asm volatile("s_waitcnt vmcnt(16)" ::: "memory"); }
        if (t < TPB-1) {
            SCHED_FENCE();
            __builtin_amdgcn_s_barrier();
            SCHED_FENCE();
        }
    }
}

extern "C" void kernel_launch(void* const* d_in, const int* in_sizes, int n_in,
                              void* d_out, int out_size, void* d_ws, size_t ws_size,
                              hipStream_t stream) {
    const float* H  = (const float*)d_in[0];   // [8,4096,1024] f32
    const float* Qf = (const float*)d_in[1];   // [1024,16] f32, orthonormal cols
    float* outp     = (float*)d_out;
    const int nrows  = in_sizes[0] / HID;      // 32768
    const int ntiles = nrows / TM;             // 2048

    short* Qt = (short*)d_ws;                  // 32 KB
    short* Qa = Qt + 16*HID;                   // 32 KB (permuted)

    hipLaunchKernelGGL(q_setup, dim3(64), dim3(256), 0, stream, Qf, Qt, Qa);

    // 136KB LDS -> exactly 1 block/CU; 256 blocks, 8 tiles each, DMA-pipelined
    hipLaunchKernelGGL(probe_removal_dma, dim3(ntiles / TPB), dim3(NW*64), 0, stream,
                       H, Qt, Qa, outp);
}

// Round 15
// 57.921 us; speedup vs baseline: 1.2659x; 1.0034x over previous
//
#include <hip/hip_runtime.h>
#include <hip/hip_bf16.h>

constexpr int HID = 1024;
constexpr int KD  = 16;    // probe directions
constexpr int TM  = 16;    // rows per tile
constexpr int NW  = 8;     // waves per block (each owns a 128-wide col slice)
constexpr int TPB = 8;     // tiles per block (2048 tiles / 256 blocks)

typedef short bf16x8 __attribute__((ext_vector_type(8)));   // MFMA A/B frag
typedef float f32x4  __attribute__((ext_vector_type(4)));   // MFMA C/D frag

__device__ __forceinline__ short f2b(float x) {
    __hip_bfloat16 b = __float2bfloat16(x);
    return *reinterpret_cast<short*>(&b);
}
__device__ __forceinline__ float b2f(short s) {
    return __uint_as_float(((unsigned int)(unsigned short)s) << 16);
}

// Qt[r][k] = bf16(Q[k][r]) (16x1024): coef B-frags, 16B contiguous reads.
// Qa permuted (64x16x16) for the 8-wave/128-col geometry: epilogue MFMA's
// D-layout lands exactly on the coef A-frag register layout:
//   jslot = w*8 + jl (w=0..7, jl=0..7), p=jl>>1, odd=jl&1
//   col(jslot, rr) = w*128 + p*32 + (rr>>2)*8 + odd*4 + (rr&3)
__global__ void q_setup(const float* __restrict__ Qf,
                        short* __restrict__ Qt, short* __restrict__ Qa) {
    const int idx = blockIdx.x*256 + threadIdx.x;
    if (idx < 16*HID) {
        const int r = idx >> 10, k = idx & 1023;
        Qt[idx] = f2b(Qf[k*KD + r]);
        const int gs = idx >> 4, dir = idx & 15;
        const int jslot = gs >> 4, rr = gs & 15;
        const int w = jslot >> 3, jl = jslot & 7;
        const int p = jl >> 1, odd = jl & 1;
        const int col = w*128 + p*32 + (rr >> 2)*8 + odd*4 + (rr & 3);
        Qa[idx] = f2b(Qf[col*KD + dir]);
    }
}

#define SCHED_FENCE() __builtin_amdgcn_sched_barrier(0)

// Stage one 64KB H tile via global_load_lds: wave w stages rows w*2..w*2+1.
// 16B-piece swizzle ^ (row&7) applied on the GLOBAL source address (LDS dest
// linear, as required); coef ds_read applies the same XOR.
__device__ __forceinline__ void stage_tile(float* ldsBuf, const float* Hbase,
                                           int w, int lane) {
    #pragma unroll
    for (int i = 0; i < 8; ++i) {
        const int rr = w*2 + (i >> 2);
        const int qq = i & 3;
        const int s  = qq*64 + lane;                  // lds piece slot
        const float* g = Hbase + rr*1024 + ((s ^ (rr & 7)) << 2);
        const float* l = ldsBuf + rr*1024 + qq*256;   // wave-uniform base; HW adds lane*16
        __builtin_amdgcn_global_load_lds(
            (const __attribute__((address_space(1))) void*)g,
            (__attribute__((address_space(3))) void*)l, 16, 0, 0);
    }
}

__global__ __launch_bounds__(NW*64)
void probe_removal_dma8(const float* __restrict__ H,
                        const short* __restrict__ Qt,
                        const short* __restrict__ Qa,
                        float* __restrict__ out)
{
    const int lane = threadIdx.x & 63;
    const int w    = threadIdx.x >> 6;   // wave: col slice [w*128, w*128+128)
    const int r    = lane & 15;
    const int q    = lane >> 4;

    __shared__ __align__(16) float Hb[2][TM][HID];   // 128 KB double buffer
    __shared__ __align__(16) float ctr[NW][TM][20];  // coef partials
    __shared__ float s2p[NW][TM];

    const int tile0 = blockIdx.x * TPB;

    // ---- persistent Q fragments (48 VGPR; 2 waves/SIMD -> budget 256) ----
    bf16x8 bq[4];                       // coef B-frag per kt
    #pragma unroll
    for (int kt = 0; kt < 4; ++kt)
        bq[kt] = *reinterpret_cast<const bf16x8*>(Qt + r*1024 + w*128 + q*8 + kt*32);
    bf16x8 aq0[4], aq1[4];              // epilogue A-frag pairs (permuted Qa)
    #pragma unroll
    for (int p = 0; p < 4; ++p) {
        if (q < 2) {
            aq0[p] = *reinterpret_cast<const bf16x8*>(Qa + ((w*8 + 2*p    )*16 + r)*KD + q*8);
            aq1[p] = *reinterpret_cast<const bf16x8*>(Qa + ((w*8 + 2*p + 1)*16 + r)*KD + q*8);
        } else {
            #pragma unroll
            for (int i = 0; i < 8; ++i) { aq0[p][i] = 0; aq1[p][i] = 0; }
        }
    }
    SCHED_FENCE();

    // ---- prologue: stage tiles 0 and 1 (8 loads each per wave) ----
    stage_tile(&Hb[0][0][0], H + (size_t)tile0*TM*HID, w, lane);
    SCHED_FENCE();
    stage_tile(&Hb[1][0][0], H + (size_t)(tile0+1)*TM*HID, w, lane);
    SCHED_FENCE();
    asm volatile("s_waitcnt vmcnt(8)" ::: "memory");   // tile 0 landed (tile 1 in flight)
    SCHED_FENCE();
    __builtin_amdgcn_s_barrier();

    #pragma unroll
    for (int t = 0; t < TPB; ++t) {
        const int cur = t & 1;
        const char* HbC = (const char*)&Hb[cur][0][0];

        // ---- coef GEMM from LDS (swizzled b128 reads); af = h slice in regs ----
        bf16x8 af[4];
        f32x4 acc0 = {0.f,0.f,0.f,0.f}, acc1 = {0.f,0.f,0.f,0.f};
        float s2 = 0.f;
        #pragma unroll
        for (int kt = 0; kt < 4; ++kt) {
            const int P  = w*32 + kt*8 + q*2;       // even piece index
            const int sx = P ^ (r & 7);
            const float4 x = *(const float4*)(HbC + r*4096 + sx*16);
            const float4 y = *(const float4*)(HbC + r*4096 + (sx^1)*16);
            s2 = fmaf(x.x,x.x, fmaf(x.y,x.y, fmaf(x.z,x.z, fmaf(x.w,x.w, s2))));
            s2 = fmaf(y.x,y.x, fmaf(y.y,y.y, fmaf(y.z,y.z, fmaf(y.w,y.w, s2))));
            bf16x8 a;
            a[0]=f2b(x.x); a[1]=f2b(x.y); a[2]=f2b(x.z); a[3]=f2b(x.w);
            a[4]=f2b(y.x); a[5]=f2b(y.y); a[6]=f2b(y.z); a[7]=f2b(y.w);
            af[kt] = a;
            if (kt & 1) acc1 = __builtin_amdgcn_mfma_f32_16x16x32_bf16(a, bq[kt], acc1, 0, 0, 0);
            else        acc0 = __builtin_amdgcn_mfma_f32_16x16x32_bf16(a, bq[kt], acc0, 0, 0, 0);
        }
        const f32x4 acc = acc0 + acc1;
        s2 += __shfl_xor(s2, 16);
        s2 += __shfl_xor(s2, 32);

        #pragma unroll
        for (int i = 0; i < 4; ++i) ctr[w][q*4 + i][r] = acc[i];
        if (q == 0) s2p[w][r] = s2;

        // ctr visible to all waves; raw barrier does NOT drain vmcnt:
        asm volatile("s_waitcnt lgkmcnt(0)" ::: "memory");
        SCHED_FENCE();
        __builtin_amdgcn_s_barrier();
        SCHED_FENCE();

        // ---- stage tile t+2 into the freed buffer ----
        if (t + 2 < TPB)
            stage_tile(&Hb[cur][0][0], H + (size_t)(tile0+t+2)*TM*HID, w, lane);
        SCHED_FENCE();

        // ---- cross-wave reduce -> coefs, scale, pb ----
        float cf[8] = {0,0,0,0,0,0,0,0};
        if (q < 2) {
            #pragma unroll
            for (int w2 = 0; w2 < NW; ++w2) {
                const float4 a = *reinterpret_cast<const float4*>(&ctr[w2][r][q*8]);
                const float4 b = *reinterpret_cast<const float4*>(&ctr[w2][r][q*8 + 4]);
                cf[0]+=a.x; cf[1]+=a.y; cf[2]+=a.z; cf[3]+=a.w;
                cf[4]+=b.x; cf[5]+=b.y; cf[6]+=b.z; cf[7]+=b.w;
            }
        }
        float s2tot = 0.f;
        #pragma unroll
        for (int w2 = 0; w2 < NW; ++w2) s2tot += s2p[w2][r];

        float sc2 = 0.f;
        #pragma unroll
        for (int i = 0; i < 8; ++i) sc2 = fmaf(cf[i], cf[i], sc2);
        sc2 += __shfl_xor(sc2, 16);
        sc2 += __shfl_xor(sc2, 32);
        const float scale = rsqrtf(fmaxf(1.0f - sc2 / s2tot, 1e-20f));

        bf16x8 pb;
        #pragma unroll
        for (int i = 0; i < 8; ++i) pb[i] = f2b(cf[i]);

        // ---- fused epilogue: all operands in registers; 8 stores per lane ----
        float* orow = out + (size_t)(tile0+t)*TM*HID + r*HID + w*128;
        const f32x4 zero4 = {0.f,0.f,0.f,0.f};
        #pragma unroll
        for (int p = 0; p < 4; ++p) {
            const f32x4 d0 = __builtin_amdgcn_mfma_f32_16x16x32_bf16(aq0[p], pb, zero4, 0, 0, 0);
            const f32x4 d1 = __builtin_amdgcn_mfma_f32_16x16x32_bf16(aq1[p], pb, zero4, 0, 0, 0);
            f32x4 o0, o1;
            #pragma unroll
            for (int ii = 0; ii < 4; ++ii) {
                o0[ii] = (b2f(af[p][ii])     - d0[ii]) * scale;
                o1[ii] = (b2f(af[p][4 + ii]) - d1[ii]) * scale;
            }
            *reinterpret_cast<f32x4*>(orow + p*32 + q*8)     = o0;
            *reinterpret_cast<f32x4*>(orow + p*32 + q*8 + 4) = o1;
        }
        SCHED_FENCE();

        // ---- counted drain: stage(t+1) landed; stage(t+2)+stores(t) stay
        //      in flight (never vmcnt(0) mid-loop) ----
        if (t < TPB-1) {
            asm volatile("s_waitcnt vmcnt(16)" ::: "memory");
            SCHED_FENCE();
            __builtin_amdgcn_s_barrier();
            SCHED_FENCE();
        }
    }
}

extern "C" void kernel_launch(void* const* d_in, const int* in_sizes, int n_in,
                              void* d_out, int out_size, void* d_ws, size_t ws_size,
                              hipStream_t stream) {
    const float* H  = (const float*)d_in[0];   // [8,4096,1024] f32
    const float* Qf = (const float*)d_in[1];   // [1024,16] f32, orthonormal cols
    float* outp     = (float*)d_out;
    const int nrows  = in_sizes[0] / HID;      // 32768
    const int ntiles = nrows / TM;             // 2048

    short* Qt = (short*)d_ws;                  // 32 KB
    short* Qa = Qt + 16*HID;                   // 32 KB (permuted)

    hipLaunchKernelGGL(q_setup, dim3(64), dim3(256), 0, stream, Qf, Qt, Qa);

    // 139KB LDS -> 1 block/CU, but 8 waves -> 2 waves/SIMD (2x R14 TLP)
    hipLaunchKernelGGL(probe_removal_dma8, dim3(ntiles / TPB), dim3(NW*64), 0, stream,
                       H, Qt, Qa, outp);
}